// Round 8
// baseline (778.723 us; speedup 1.0000x reference)
//
#include <hip/hip_runtime.h>

// Problem dims (fixed by reference setup_inputs)
#define BB   2
#define CF_  64
#define CC   3
#define HH   64
#define WW   2048
#define HWs  (HH * WW)      // 131072
#define KK   9
#define NPL  (BB * CF_ * KK)  // 1152 output planes

typedef float f4 __attribute__((ext_vector_type(4)));

// out[b, cf*9+n, h, w] = feat[b,cf,h+di,w+dj] * relu(M[cf,:]·rel[:,n])
// M = w1 @ w0;  rel_c = (cen_c==-1) ? 0 : s_c - cen_c
//   => M·rel = Σ k_c·s_c − Σ k_c·cen_c,  k_c = (cen_c!=-1) ? m_c : 0
// OOB taps: reference zero-pads FEATURES -> out=0 regardless of weight.
//
// THEORY-C STRUCTURE: thread p writes out bytes [16p,16p+16) — the write
// stream is GLOBALLY linear, byte-for-byte the fillBufferAligned pattern
// that measures 6.27 TB/s. All reads are L3-resident (feat 67 MB, coord
// 3 MB < 256 MB), so HBM traffic = 604 MB write + ~70 MB compulsory read.
__global__ __launch_bounds__(256) void fused_unfold_mlp_kernel(
    const float* __restrict__ feat,
    const float* __restrict__ coord,
    const float* __restrict__ w0,
    const float* __restrict__ w1,
    float* __restrict__ out)
{
    const int t   = threadIdx.x;
    const int bid = blockIdx.x;           // consecutive bid = consecutive 4 KB of out
    const int whalf = bid & 1;
    const int h     = (bid >> 1) & (HH - 1);
    const int rest  = bid >> 7;           // = b*576 + cf*9 + n  (plane index)
    const int b     = rest >= (CF_ * KK);
    const int pn    = rest - b * (CF_ * KK);
    const int cf    = pn / KK;            // block-uniform scalar div
    const int n     = pn - cf * KK;
    const int di    = n / 3 - 1;
    const int dj    = n % 3 - 1;

    const int w0c = (whalf * 256 + t) * 4;      // this thread's 4 output cols
    f4* __restrict__ ost = (f4*)(out + (size_t)rest * HWs + (size_t)h * WW + w0c);

    const int hh = h + di;
    if (hh < 0 || hh >= HH) {             // uniform: whole plane-row is zero
        f4 z = {0.f, 0.f, 0.f, 0.f};
        *ost = z;                          // plain store, same path as the rest
        return;
    }

    // M row for this cf (block-uniform; scalar loads, tiny)
    float m0a = 0.f, m1a = 0.f, m2a = 0.f;
#pragma unroll
    for (int k = 0; k < 16; k++) {
        const float a = w1[cf * 16 + k];
        m0a = fmaf(a, w0[k * CC + 0], m0a);
        m1a = fmaf(a, w0[k * CC + 1], m1a);
        m2a = fmaf(a, w0[k * CC + 2], m2a);
    }

    // sample/feature window: desired cols w0c+dj .. w0c+dj+3; clamp the base
    // at the two edge threads and repair with compile-time-indexed selects
    const bool eL = (w0c == 0)      && (dj < 0);
    const bool eR = (w0c == WW - 4) && (dj > 0);
    const int  ws = w0c + dj + (eL ? 1 : 0) - (eR ? 1 : 0);

    const float* __restrict__ cb = coord + (size_t)b * CC * HWs;
    const float* __restrict__ fp = feat + ((size_t)b * CF_ + cf) * HWs;

    f4 cen[CC], raw[CC];
#pragma unroll
    for (int c = 0; c < CC; c++) {
        cen[c] = *(const f4*)(cb + (size_t)c * HWs + (size_t)h  * WW + w0c);
        raw[c] = *(const f4*)(cb + (size_t)c * HWs + (size_t)hh * WW + ws);
    }
    const f4 fraw = *(const f4*)(fp + (size_t)hh * WW + ws);

    // edge repair: eL -> window shifted +1 (px0 dead), eR -> shifted -1 (px3 dead)
    float s[CC][4], ft[4];
#pragma unroll
    for (int px = 0; px < 4; px++) {
#pragma unroll
        for (int c = 0; c < CC; c++)
            s[c][px] = eL ? (px >= 1 ? raw[c][px - 1] : 0.f)
                     : eR ? (px <= 2 ? raw[c][px + 1] : 0.f)
                     :      raw[c][px];
        ft[px] = eL ? (px >= 1 ? fraw[px - 1] : 0.f)
               : eR ? (px <= 2 ? fraw[px + 1] : 0.f)
               :      fraw[px];
    }

    f4 v;
#pragma unroll
    for (int px = 0; px < 4; px++) {
        const float k0 = (cen[0][px] != -1.f) ? m0a : 0.f;
        const float k1 = (cen[1][px] != -1.f) ? m1a : 0.f;
        const float k2 = (cen[2][px] != -1.f) ? m2a : 0.f;
        const float bb = fmaf(k2, cen[2][px], fmaf(k1, cen[1][px], k0 * cen[0][px]));
        float wgt = fmaf(k2, s[2][px], fmaf(k1, s[1][px], fmaf(k0, s[0][px], -bb)));
        v[px] = ft[px] * fmaxf(wgt, 0.f);
    }
    *ost = v;   // plain f4 store — byte-for-byte the fill kernel's write pattern
}

extern "C" void kernel_launch(void* const* d_in, const int* in_sizes, int n_in,
                              void* d_out, int out_size, void* d_ws, size_t ws_size,
                              hipStream_t stream) {
    const float* feat  = (const float*)d_in[0];
    const float* coord = (const float*)d_in[1];
    const float* w0    = (const float*)d_in[2];
    const float* w1    = (const float*)d_in[3];
    float* out = (float*)d_out;

    // one thread per 16 output bytes: 1152 planes * 64 rows * 2 half-rows
    const int blocks = NPL * HH * 2;    // 147456 blocks of 256 threads
    fused_unfold_mlp_kernel<<<blocks, 256, 0, stream>>>(feat, coord, w0, w1, out);
}

// Round 10
// 759.358 us; speedup vs baseline: 1.0255x; 1.0255x over previous
//
#include <hip/hip_runtime.h>

// Problem dims (fixed by reference setup_inputs)
#define BB   2
#define CF_  64
#define CC   3
#define HH   64
#define WW   2048
#define HWs  (HH * WW)      // 131072
#define KK   9
#define CH   4              // channels per thread
#define NQ   (CF_ / CH)     // 16 channel slices
#define PX   2              // pixels per thread (float2 stores)
// TELEMETRY ROUND: run the whole body REPS times (idempotent re-store) to
// discriminate "kernel ~285us" vs "kernel ~110us + fixed harness cost".
#define REPS 2

typedef float f2 __attribute__((ext_vector_type(2)));
typedef float f4 __attribute__((ext_vector_type(4)));

// out[b, cf*9+n, h, w] = feat[b,cf,h+di,w+dj] * relu(M[cf,:]·rel[:,n])
// M = w1 @ w0;  rel[c,n] = (center_c==-1) ? 0 : sample_c,n - center_c
// Identity: M·rel = Σc (m_c k_c)·s_c − Σc m_c k_c center_c   (k_c = center_c != -1)
// OOB taps: reference zero-pads FEATURES, so zeroing the feature tap forces
// out=0 regardless of the (garbage) coord sample.
__global__ __launch_bounds__(256) void fused_unfold_mlp_kernel(
    const float* __restrict__ feat,
    const float* __restrict__ coord,
    const float* __restrict__ w0,
    const float* __restrict__ w1,
    float* __restrict__ out)
{
    __shared__ float Msh[CH * CC];   // this block's 4 rows of M = w1@w0

    const int t  = threadIdx.x;
    const int id   = blockIdx.x;
    const int wseg = id & 3;
    const int b    = (id >> 2) & 1;
    const int q    = (id >> 3) & (NQ - 1);
    const int h    = id >> 7;
    const int cfbase = q * CH;

    if (t < CH * CC) {
        const int o = t / CC, c = t - o * CC;
        float acc = 0.f;
#pragma unroll
        for (int k = 0; k < 16; k++)
            acc = fmaf(w1[(cfbase + o) * 16 + k], w0[k * CC + c], acc);
        Msh[t] = acc;
    }
    __syncthreads();

    float ms[CH * CC];
#pragma unroll
    for (int j = 0; j < CH * CC; j++)
        ms[j] = __uint_as_float(__builtin_amdgcn_readfirstlane(__float_as_uint(Msh[j])));

    const int  w0p = (wseg * 256 + t) * PX;     // first of 2 pixels
    const bool eL  = (w0p == 0);
    const bool eR  = (w0p == WW - PX);
    const int  base = eL ? 0 : (eR ? (WW - 4) : (w0p - 1));

    int rows[3];
    rows[0] = (h > 0      ? h - 1 : 0     ) * WW;
    rows[1] = h * WW;
    rows[2] = (h < HH - 1 ? h + 1 : HH - 1) * WW;

    const float* __restrict__ cb = coord + (size_t)b * CC * HWs;
    const float* __restrict__ fb = feat + (size_t)b * CF_ * HWs;
    f2* __restrict__ ob2 = (f2*)(out
        + (size_t)(b * CF_ + cfbase) * KK * HWs + (size_t)h * WW + w0p);

    for (int rep = 0; rep < REPS; ++rep) {
        // ---- coord taps ct[c][r][4] ----
        float ct[CC][3][4];
#pragma unroll
        for (int c = 0; c < CC; c++) {
            const float* cc = cb + (size_t)c * HWs;
#pragma unroll
            for (int r = 0; r < 3; r++) {
                const f4 ld = *(const f4*)(cc + rows[r] + base);
                ct[c][r][0] = eR ? ld[1] : ld[0];
                ct[c][r][1] = eL ? ld[0] : (eR ? ld[2] : ld[1]);
                ct[c][r][2] = eL ? ld[1] : (eR ? ld[3] : ld[2]);
                ct[c][r][3] = eL ? ld[2] : ld[3];
            }
        }

        // ---- feature taps ft[CH][3][4]; OOB columns zeroed ----
        float ft[CH][3][4];
#pragma unroll
        for (int i = 0; i < CH; i++) {
            const float* fc = fb + (size_t)(cfbase + i) * HWs;
#pragma unroll
            for (int r = 0; r < 3; r++) {
                const f4 ld = *(const f4*)(fc + rows[r] + base);
                ft[i][r][0] = eL ? 0.f : (eR ? ld[1] : ld[0]);
                ft[i][r][1] = eL ? ld[0] : (eR ? ld[2] : ld[1]);
                ft[i][r][2] = eL ? ld[1] : (eR ? ld[3] : ld[2]);
                ft[i][r][3] = eR ? 0.f : (eL ? ld[2] : ld[3]);
            }
        }
        if (h == 0) {
#pragma unroll
            for (int i = 0; i < CH; i++)
#pragma unroll
                for (int jj = 0; jj < 4; jj++) ft[i][0][jj] = 0.f;
        }
        if (h == HH - 1) {
#pragma unroll
            for (int i = 0; i < CH; i++)
#pragma unroll
                for (int jj = 0; jj < 4; jj++) ft[i][2][jj] = 0.f;
        }

        // ---- centers & masks ----
        float kf[CC][PX], mcv[CC][PX];
#pragma unroll
        for (int c = 0; c < CC; c++)
#pragma unroll
            for (int px = 0; px < PX; px++) {
                const float cen = ct[c][1][1 + px];
                const float k   = (cen != -1.0f) ? 1.0f : 0.0f;
                kf[c][px]  = k;
                mcv[c][px] = k * cen;
            }

        // ---- compute + 36 stores ----
#pragma unroll
        for (int i = 0; i < CH; i++) {
            const float m0 = ms[i * CC + 0], m1 = ms[i * CC + 1], m2 = ms[i * CC + 2];
            float mk[CC][PX], bbv[PX];
#pragma unroll
            for (int px = 0; px < PX; px++) {
                mk[0][px] = m0 * kf[0][px];
                mk[1][px] = m1 * kf[1][px];
                mk[2][px] = m2 * kf[2][px];
                bbv[px] = fmaf(m2, mcv[2][px], fmaf(m1, mcv[1][px], m0 * mcv[0][px]));
            }
#pragma unroll
            for (int n = 0; n < KK; n++) {
                const int r = n / 3, j = n % 3;
                f2 v;
#pragma unroll
                for (int px = 0; px < PX; px++) {
                    const int jj = px + j;
                    float wgt = fmaf(mk[2][px], ct[2][r][jj],
                                fmaf(mk[1][px], ct[1][r][jj],
                                fmaf(mk[0][px], ct[0][r][jj], -bbv[px])));
                    v[px] = ft[i][r][jj] * fmaxf(wgt, 0.0f);
                }
                __builtin_nontemporal_store(v, ob2 + (size_t)(i * KK + n) * (HWs / 2));
            }
        }
        // Force pass separation: loads reload, pass-1 stores not elided.
        asm volatile("" ::: "memory");
    }
}

extern "C" void kernel_launch(void* const* d_in, const int* in_sizes, int n_in,
                              void* d_out, int out_size, void* d_ws, size_t ws_size,
                              hipStream_t stream) {
    const float* feat  = (const float*)d_in[0];
    const float* coord = (const float*)d_in[1];
    const float* w0    = (const float*)d_in[2];
    const float* w1    = (const float*)d_in[3];
    float* out = (float*)d_out;

    const int total  = BB * HH * (WW / PX) * NQ;   // 2097152 threads
    const int blocks = total / 256;                 // 8192 blocks
    fused_unfold_mlp_kernel<<<blocks, 256, 0, stream>>>(feat, coord, w0, w1, out);
}